// Round 4
// baseline (806.001 us; speedup 1.0000x reference)
//
#include <hip/hip_runtime.h>
#include <hip/hip_bf16.h>

// Problem: out[M=4096][N=16384] = x[M][K=4096] @ (W[N][K] * scale[N/128][K/128])^T + bias[N]
#define M_DIM 4096
#define N_DIM 16384
#define K_DIM 4096

typedef __bf16 bf16x8 __attribute__((ext_vector_type(8)));
typedef float f32x4 __attribute__((ext_vector_type(4)));

__device__ __forceinline__ void gload16(const void* g, void* l) {
    __builtin_amdgcn_global_load_lds((__attribute__((address_space(1))) void*)g,
                                     (__attribute__((address_space(3))) void*)l, 16, 0, 0);
}

// ---------- prepass 1: x fp32 -> bf16 ----------
__global__ __launch_bounds__(256) void cvt_x_kernel(const float* __restrict__ x,
                                                    __hip_bfloat16* __restrict__ out,
                                                    int ngroups) {
    int i = blockIdx.x * blockDim.x + threadIdx.x;
    int stride = gridDim.x * blockDim.x;
    for (; i < ngroups; i += stride) {
        const float4* p = (const float4*)(x + (size_t)i * 8);
        float4 v0 = p[0];
        float4 v1 = p[1];
        bf16x8 r;
        r[0] = (__bf16)v0.x; r[1] = (__bf16)v0.y; r[2] = (__bf16)v0.z; r[3] = (__bf16)v0.w;
        r[4] = (__bf16)v1.x; r[5] = (__bf16)v1.y; r[6] = (__bf16)v1.z; r[7] = (__bf16)v1.w;
        *(bf16x8*)(out + (size_t)i * 8) = r;
    }
}

// ---------- prepass 2: W fp32 * blockscale -> bf16 ----------
__global__ __launch_bounds__(256) void dequant_w_kernel(const float* __restrict__ w,
                                                        const float* __restrict__ scale,
                                                        __hip_bfloat16* __restrict__ out) {
    const int ngroups = N_DIM * (K_DIM / 8);
    int i = blockIdx.x * blockDim.x + threadIdx.x;
    int stride = gridDim.x * blockDim.x;
    for (; i < ngroups; i += stride) {
        int row = i >> 9;            // K/8 = 512 groups per row
        int cg  = i & 511;
        float s = scale[(row >> 7) * (K_DIM / 128) + (cg >> 4)];
        const float4* p = (const float4*)(w + (size_t)i * 8);
        float4 v0 = p[0];
        float4 v1 = p[1];
        bf16x8 r;
        r[0] = (__bf16)(v0.x * s); r[1] = (__bf16)(v0.y * s);
        r[2] = (__bf16)(v0.z * s); r[3] = (__bf16)(v0.w * s);
        r[4] = (__bf16)(v1.x * s); r[5] = (__bf16)(v1.y * s);
        r[6] = (__bf16)(v1.z * s); r[7] = (__bf16)(v1.w * s);
        *(bf16x8*)(out + (size_t)i * 8) = r;
    }
}

// ---------- main GEMM: 256x256 tile, BK=64, 8 waves, 4-phase m201 cadence ----------
// Per K-tile: 4 phases, each {stage 2 gloads of tile t+1; [vmcnt(4) at P1,P2];
// s_barrier; ds_read 8|4 b128; lgkmcnt(0); setprio(1) 16 MFMA setprio(0)}.
// Stage order B0B1|B2B3|A0A2|A1A3; read needs: P1 {A0/A2,B*}, P2 {A1/A3}.
// In-order vmcnt retire (m135): vmcnt(4) at P1 => all but {A1A3, new B0B1}
// done; at P2 => all but 4 new B-chunks done. vmcnt->barrier makes it
// collective; reads issue after the barrier (sched_barrier(0) pins them).
// Never drains vmcnt to 0 in the steady loop (last iter peeled, ST=false).
template <bool ST>
__device__ __forceinline__ void kstep(const __hip_bfloat16* __restrict__ pa,
                                      const __hip_bfloat16* __restrict__ pb,
                                      const __hip_bfloat16* __restrict__ aN,
                                      const __hip_bfloat16* __restrict__ bN,
                                      char* lAn, char* lBn,
                                      f32x4 (&acc)[8][4],
                                      int arow, int brow, int c0, int c1,
                                      int srow) {
    const size_t K = K_DIM;
    bf16x8 av[4], bv[4], b1[4];

    // ===== P1: stage B0,B1 ; vmcnt(4) ; bar ; read a-low,b (8) ; 16 MFMA =====
    if (ST) {
        gload16(bN + (size_t)(0 * 64 + srow) * K, lBn + 0 * 8192);
        gload16(bN + (size_t)(1 * 64 + srow) * K, lBn + 1 * 8192);
        asm volatile("s_waitcnt vmcnt(4)" ::: "memory");
    } else {
        asm volatile("s_waitcnt vmcnt(0)" ::: "memory");
    }
    __builtin_amdgcn_s_barrier();
    __builtin_amdgcn_sched_barrier(0);
    #pragma unroll
    for (int i = 0; i < 4; ++i) {
        av[i] = *(const bf16x8*)(pa + arow + i * 1024 + c0);
        bv[i] = *(const bf16x8*)(pb + brow + i * 1024 + c0);
    }
    asm volatile("s_waitcnt lgkmcnt(0)" ::: "memory");
    __builtin_amdgcn_sched_barrier(0);
    __builtin_amdgcn_s_setprio(1);
    #pragma unroll
    for (int mi = 0; mi < 4; ++mi)
        #pragma unroll
        for (int ni = 0; ni < 4; ++ni)
            acc[mi][ni] = __builtin_amdgcn_mfma_f32_16x16x32_bf16(av[mi], bv[ni], acc[mi][ni], 0, 0, 0);
    __builtin_amdgcn_s_setprio(0);
    __builtin_amdgcn_sched_barrier(0);

    // ===== P2: stage B2,B3 ; vmcnt(4) ; bar ; read a-high (4) ; 16 MFMA =====
    if (ST) {
        gload16(bN + (size_t)(2 * 64 + srow) * K, lBn + 2 * 8192);
        gload16(bN + (size_t)(3 * 64 + srow) * K, lBn + 3 * 8192);
        asm volatile("s_waitcnt vmcnt(4)" ::: "memory");
    } else {
        asm volatile("s_waitcnt vmcnt(0)" ::: "memory");
    }
    __builtin_amdgcn_s_barrier();
    __builtin_amdgcn_sched_barrier(0);
    #pragma unroll
    for (int i = 0; i < 4; ++i)
        av[i] = *(const bf16x8*)(pa + arow + 4096 + i * 1024 + c0);
    asm volatile("s_waitcnt lgkmcnt(0)" ::: "memory");
    __builtin_amdgcn_sched_barrier(0);
    __builtin_amdgcn_s_setprio(1);
    #pragma unroll
    for (int mi = 0; mi < 4; ++mi)
        #pragma unroll
        for (int ni = 0; ni < 4; ++ni)
            acc[4 + mi][ni] = __builtin_amdgcn_mfma_f32_16x16x32_bf16(av[mi], bv[ni], acc[4 + mi][ni], 0, 0, 0);
    __builtin_amdgcn_s_setprio(0);
    __builtin_amdgcn_sched_barrier(0);

    // ===== P3: stage A0,A2 ; bar ; read a-low,b kk1 (8) ; 16 MFMA =====
    if (ST) {
        gload16(aN + (size_t)(0 * 64 + srow) * K, lAn + 0 * 8192);
        gload16(aN + (size_t)(2 * 64 + srow) * K, lAn + 2 * 8192);
    }
    __builtin_amdgcn_s_barrier();
    __builtin_amdgcn_sched_barrier(0);
    #pragma unroll
    for (int i = 0; i < 4; ++i) {
        av[i] = *(const bf16x8*)(pa + arow + i * 1024 + c1);
        b1[i] = *(const bf16x8*)(pb + brow + i * 1024 + c1);
    }
    asm volatile("s_waitcnt lgkmcnt(0)" ::: "memory");
    __builtin_amdgcn_sched_barrier(0);
    __builtin_amdgcn_s_setprio(1);
    #pragma unroll
    for (int mi = 0; mi < 4; ++mi)
        #pragma unroll
        for (int ni = 0; ni < 4; ++ni)
            acc[mi][ni] = __builtin_amdgcn_mfma_f32_16x16x32_bf16(av[mi], b1[ni], acc[mi][ni], 0, 0, 0);
    __builtin_amdgcn_s_setprio(0);
    __builtin_amdgcn_sched_barrier(0);

    // ===== P4: stage A1,A3 ; bar ; read a-high kk1 (4) ; 16 MFMA =====
    if (ST) {
        gload16(aN + (size_t)(1 * 64 + srow) * K, lAn + 1 * 8192);
        gload16(aN + (size_t)(3 * 64 + srow) * K, lAn + 3 * 8192);
    }
    __builtin_amdgcn_s_barrier();
    __builtin_amdgcn_sched_barrier(0);
    #pragma unroll
    for (int i = 0; i < 4; ++i)
        av[i] = *(const bf16x8*)(pa + arow + 4096 + i * 1024 + c1);
    asm volatile("s_waitcnt lgkmcnt(0)" ::: "memory");
    __builtin_amdgcn_sched_barrier(0);
    __builtin_amdgcn_s_setprio(1);
    #pragma unroll
    for (int mi = 0; mi < 4; ++mi)
        #pragma unroll
        for (int ni = 0; ni < 4; ++ni)
            acc[4 + mi][ni] = __builtin_amdgcn_mfma_f32_16x16x32_bf16(av[mi], b1[ni], acc[4 + mi][ni], 0, 0, 0);
    __builtin_amdgcn_s_setprio(0);
    __builtin_amdgcn_sched_barrier(0);
}

__global__ __launch_bounds__(512, 2)
void gemm_bf16_kernel(const __hip_bfloat16* __restrict__ A,   // [M][K] bf16
                      const __hip_bfloat16* __restrict__ Bw,  // [N][K] bf16
                      const float* __restrict__ bias,
                      float* __restrict__ C) {                // [M][N] fp32
    constexpr int Mtiles = M_DIM / 256;            // 16
    constexpr int Ntiles = N_DIM / 256;            // 64
    constexpr int nwg = Mtiles * Ntiles;           // 1024 (div by 8)
    constexpr int NT = K_DIM / 64;                 // 64 K-tiles

    int bid = blockIdx.x;
    int swz = (bid & 7) * (nwg >> 3) + (bid >> 3);   // bijective XCD swizzle
    int bm = swz % Mtiles;
    int bn = swz / Mtiles;

    __shared__ __align__(16) __hip_bfloat16 sA[2][256 * 64];   // 64 KiB
    __shared__ __align__(16) __hip_bfloat16 sB[2][256 * 64];   // 64 KiB

    const int t = threadIdx.x;
    const int l = t & 63;
    const int w = t >> 6;        // wave 0..7
    const int wm = w >> 2;       // 0..1  (M half)
    const int wn = w & 3;        // 0..3  (N quarter)

    const int lr = l & 15;
    const int lk = l >> 4;
    const int rx = (lr & 7) << 3;          // read-side element-col XOR

    // staging (rule #21): linear LDS dest, pre-swizzled global source col.
    const int srow = w * 8 + (l >> 3);
    const int scol = ((l & 7) ^ (l >> 3)) << 3;

    const size_t K = K_DIM;
    const __hip_bfloat16* aB = A  + (size_t)(bm * 256) * K + scol;
    const __hip_bfloat16* bB = Bw + (size_t)(bn * 256) * K + scol;

    f32x4 acc[8][4] = {};

    const int c0 = (lk * 8) ^ rx;
    const int c1 = (32 + lk * 8) ^ rx;
    const int arow = (wm * 128 + lr) * 64;
    const int brow = (wn * 64 + lr) * 64;

    // prologue: stage tile 0 -> buf 0, full drain once
    {
        char* la_ = (char*)&sA[0][0] + w * 1024;
        char* lb_ = (char*)&sB[0][0] + w * 1024;
        #pragma unroll
        for (int j = 0; j < 4; ++j) {
            gload16(aB + (size_t)(j * 64 + srow) * K, la_ + j * 8192);
            gload16(bB + (size_t)(j * 64 + srow) * K, lb_ + j * 8192);
        }
    }
    asm volatile("s_waitcnt vmcnt(0)" ::: "memory");
    __builtin_amdgcn_s_barrier();
    __builtin_amdgcn_sched_barrier(0);

    for (int kt = 0; kt + 1 < NT; ++kt) {
        const int cur = kt & 1;
        kstep<true>(&sA[cur][0], &sB[cur][0],
                    aB + (kt + 1) * 64, bB + (kt + 1) * 64,
                    (char*)&sA[cur ^ 1][0] + w * 1024,
                    (char*)&sB[cur ^ 1][0] + w * 1024,
                    acc, arow, brow, c0, c1, srow);
    }
    {
        const int cur = (NT - 1) & 1;
        kstep<false>(&sA[cur][0], &sB[cur][0], aB, bB,
                     (char*)&sA[cur ^ 1][0] + w * 1024,
                     (char*)&sB[cur ^ 1][0] + w * 1024,
                     acc, arow, brow, c0, c1, srow);
    }

    // epilogue: C/D layout col=lane&15, row=(lane>>4)*4+reg  [m89-verified]
    const int crow0 = bm * 256 + wm * 128;
    const int ccol0 = bn * 256 + wn * 64;
    #pragma unroll
    for (int ni = 0; ni < 4; ++ni) {
        int col = ccol0 + ni * 16 + lr;
        float bv = bias[col];
        #pragma unroll
        for (int mi = 0; mi < 8; ++mi) {
            int rbase = crow0 + mi * 16 + lk * 4;
            #pragma unroll
            for (int j = 0; j < 4; ++j) {
                C[(size_t)(rbase + j) * N_DIM + col] = acc[mi][ni][j] + bv;
            }
        }
    }
}

// ---------- fallback (ws too small): fp32 LDS-tiled, correct but slow ----------
__global__ __launch_bounds__(256)
void gemm_fallback(const float* __restrict__ X, const float* __restrict__ W,
                   const float* __restrict__ scale, const float* __restrict__ bias,
                   float* __restrict__ C) {
    int bm = blockIdx.x % (M_DIM / 64);
    int bn = blockIdx.x / (M_DIM / 64);
    __shared__ float sA[64][33];
    __shared__ float sB[64][33];
    int t = threadIdx.x;
    int tx = t & 15, ty = t >> 4;
    float acc[4][4] = {};
    for (int kt = 0; kt < K_DIM / 32; ++kt) {
        float s = scale[(bn >> 1) * (K_DIM / 128) + (kt >> 2)];
        #pragma unroll
        for (int i = 0; i < 8; ++i) {
            int idx = t + i * 256;
            int r = idx >> 5, c = idx & 31;
            sA[r][c] = X[(size_t)(bm * 64 + r) * K_DIM + kt * 32 + c];
            sB[r][c] = W[(size_t)(bn * 64 + r) * K_DIM + kt * 32 + c] * s;
        }
        __syncthreads();
        #pragma unroll
        for (int k = 0; k < 32; ++k) {
            float a[4], b[4];
            #pragma unroll
            for (int i = 0; i < 4; ++i) a[i] = sA[ty * 4 + i][k];
            #pragma unroll
            for (int j = 0; j < 4; ++j) b[j] = sB[tx * 4 + j][k];
            #pragma unroll
            for (int i = 0; i < 4; ++i)
                #pragma unroll
                for (int j = 0; j < 4; ++j) acc[i][j] += a[i] * b[j];
        }
        __syncthreads();
    }
    #pragma unroll
    for (int i = 0; i < 4; ++i)
        #pragma unroll
        for (int j = 0; j < 4; ++j) {
            int row = bm * 64 + ty * 4 + i;
            int col = bn * 64 + tx * 4 + j;
            C[(size_t)row * N_DIM + col] = acc[i][j] + bias[col];
        }
}

extern "C" void kernel_launch(void* const* d_in, const int* in_sizes, int n_in,
                              void* d_out, int out_size, void* d_ws, size_t ws_size,
                              hipStream_t stream) {
    const float* x     = (const float*)d_in[0];   // [2,2048,4096]
    const float* wgt   = (const float*)d_in[1];   // [16384,4096]
    const float* scale = (const float*)d_in[2];   // [128,32]
    const float* bias  = (const float*)d_in[3];   // [16384]
    float* out = (float*)d_out;                   // [2,2048,16384]

    const size_t need = ((size_t)M_DIM * K_DIM + (size_t)N_DIM * K_DIM) * sizeof(__hip_bfloat16);
    if (ws_size >= need) {
        __hip_bfloat16* xbf = (__hip_bfloat16*)d_ws;
        __hip_bfloat16* wbf = xbf + (size_t)M_DIM * K_DIM;
        cvt_x_kernel<<<2048, 256, 0, stream>>>(x, xbf, M_DIM * K_DIM / 8);
        dequant_w_kernel<<<4096, 256, 0, stream>>>(wgt, scale, wbf);
        gemm_bf16_kernel<<<(M_DIM / 256) * (N_DIM / 256), 512, 0, stream>>>(xbf, wbf, bias, out);
    } else {
        gemm_fallback<<<(M_DIM / 64) * (N_DIM / 64), 256, 0, stream>>>(x, wgt, scale, bias, out);
    }
}

// Round 5
// 716.323 us; speedup vs baseline: 1.1252x; 1.1252x over previous
//
#include <hip/hip_runtime.h>
#include <hip/hip_bf16.h>

// Problem: out[M=4096][N=16384] = x[M][K=4096] @ (W[N][K] * scale[N/128][K/128])^T + bias[N]
#define M_DIM 4096
#define N_DIM 16384
#define K_DIM 4096

typedef __bf16 bf16x8 __attribute__((ext_vector_type(8)));
typedef float f32x4 __attribute__((ext_vector_type(4)));

__device__ __forceinline__ void gload16(const void* g, void* l) {
    __builtin_amdgcn_global_load_lds((__attribute__((address_space(1))) void*)g,
                                     (__attribute__((address_space(3))) void*)l, 16, 0, 0);
}

// ---------- prepass 1: x fp32 -> bf16 ----------
__global__ __launch_bounds__(256) void cvt_x_kernel(const float* __restrict__ x,
                                                    __hip_bfloat16* __restrict__ out,
                                                    int ngroups) {
    int i = blockIdx.x * blockDim.x + threadIdx.x;
    int stride = gridDim.x * blockDim.x;
    for (; i < ngroups; i += stride) {
        const float4* p = (const float4*)(x + (size_t)i * 8);
        float4 v0 = p[0];
        float4 v1 = p[1];
        bf16x8 r;
        r[0] = (__bf16)v0.x; r[1] = (__bf16)v0.y; r[2] = (__bf16)v0.z; r[3] = (__bf16)v0.w;
        r[4] = (__bf16)v1.x; r[5] = (__bf16)v1.y; r[6] = (__bf16)v1.z; r[7] = (__bf16)v1.w;
        *(bf16x8*)(out + (size_t)i * 8) = r;
    }
}

// ---------- prepass 2: W fp32 * blockscale -> bf16 ----------
__global__ __launch_bounds__(256) void dequant_w_kernel(const float* __restrict__ w,
                                                        const float* __restrict__ scale,
                                                        __hip_bfloat16* __restrict__ out) {
    const int ngroups = N_DIM * (K_DIM / 8);
    int i = blockIdx.x * blockDim.x + threadIdx.x;
    int stride = gridDim.x * blockDim.x;
    for (; i < ngroups; i += stride) {
        int row = i >> 9;
        int cg  = i & 511;
        float s = scale[(row >> 7) * (K_DIM / 128) + (cg >> 4)];
        const float4* p = (const float4*)(w + (size_t)i * 8);
        float4 v0 = p[0];
        float4 v1 = p[1];
        bf16x8 r;
        r[0] = (__bf16)(v0.x * s); r[1] = (__bf16)(v0.y * s);
        r[2] = (__bf16)(v0.z * s); r[3] = (__bf16)(v0.w * s);
        r[4] = (__bf16)(v1.x * s); r[5] = (__bf16)(v1.y * s);
        r[6] = (__bf16)(v1.z * s); r[7] = (__bf16)(v1.w * s);
        *(bf16x8*)(out + (size_t)i * 8) = r;
    }
}

// ---------- main GEMM: 256x256, BK=64, 8 waves, deep-slack 4-phase pipeline ----
// Staging timeline (2 LDS buffers, chunk = 64 rows):
//   iter t P1 (post-barrier): stage A1,A3 of tile t+1 -> bufW   [slack 4 phases]
//   iter t P4 (post-barrier): stage A0,A2,B0..B3 of tile t+2 -> bufR [slack 5]
// Safety theorem: arrival at phase barrier X implies that wave passed its
// previous lgkmcnt(0), so all waves past X completed all ds_reads issued
// before barrier X-1. A1/A3 rows last read at P4 -> stage after next P1 bar;
// A0/A2/B rows last read at P3 -> stage after P4 bar. Writes always hit rows
// provably dead. One vmcnt(6) per K-tile at P1: queue there = [A1A3(t) (2),
// 6 chunks of t+1] = 8; retiring to 6 makes tile t fully resident (in-order
// retire, m135). P2-P4 ds_reads at phase top (pre-barrier; buffer resident
// since P1) so read-issue overlaps laggard waves' previous MFMA cluster.
template <bool STG1, bool STG4, bool LAST>
__device__ __forceinline__ void kstep(const __hip_bfloat16* __restrict__ pa,
                                      const __hip_bfloat16* __restrict__ pb,
                                      const __hip_bfloat16* __restrict__ gA1,  // tile t+1 A (+scol)
                                      const __hip_bfloat16* __restrict__ gA2,  // tile t+2 A
                                      const __hip_bfloat16* __restrict__ gB2,  // tile t+2 B
                                      char* lAw, char* lAr, char* lBr,
                                      f32x4 (&acc)[8][4],
                                      int arow, int brow, int c0, int c1, int srow) {
    const size_t K = K_DIM;
    bf16x8 av[4], bv[4], b1[4];

    // ===== P1: vmcnt(6); bar; stage A1,A3(t+1); read a-low+b c0; MFMA lo =====
    if (LAST) asm volatile("s_waitcnt vmcnt(0)" ::: "memory");
    else      asm volatile("s_waitcnt vmcnt(6)" ::: "memory");
    __builtin_amdgcn_sched_barrier(0);
    __builtin_amdgcn_s_barrier();
    __builtin_amdgcn_sched_barrier(0);
    if (STG1) {
        gload16(gA1 + (size_t)(64 + srow) * K, lAw + 8192);        // A1
        gload16(gA1 + (size_t)(192 + srow) * K, lAw + 3 * 8192);   // A3
    }
    #pragma unroll
    for (int i = 0; i < 4; ++i) {
        av[i] = *(const bf16x8*)(pa + arow + i * 1024 + c0);
        bv[i] = *(const bf16x8*)(pb + brow + i * 1024 + c0);
    }
    asm volatile("s_waitcnt lgkmcnt(0)" ::: "memory");
    __builtin_amdgcn_sched_barrier(0);
    __builtin_amdgcn_s_setprio(1);
    #pragma unroll
    for (int mi = 0; mi < 4; ++mi)
        #pragma unroll
        for (int ni = 0; ni < 4; ++ni)
            acc[mi][ni] = __builtin_amdgcn_mfma_f32_16x16x32_bf16(av[mi], bv[ni], acc[mi][ni], 0, 0, 0);
    __builtin_amdgcn_s_setprio(0);
    __builtin_amdgcn_sched_barrier(0);

    // ===== P2: read a-high c0 (top); bar; MFMA hi =====
    #pragma unroll
    for (int i = 0; i < 4; ++i)
        av[i] = *(const bf16x8*)(pa + arow + 4096 + i * 1024 + c0);
    __builtin_amdgcn_sched_barrier(0);
    __builtin_amdgcn_s_barrier();
    asm volatile("s_waitcnt lgkmcnt(0)" ::: "memory");
    __builtin_amdgcn_sched_barrier(0);
    __builtin_amdgcn_s_setprio(1);
    #pragma unroll
    for (int mi = 0; mi < 4; ++mi)
        #pragma unroll
        for (int ni = 0; ni < 4; ++ni)
            acc[4 + mi][ni] = __builtin_amdgcn_mfma_f32_16x16x32_bf16(av[mi], bv[ni], acc[4 + mi][ni], 0, 0, 0);
    __builtin_amdgcn_s_setprio(0);
    __builtin_amdgcn_sched_barrier(0);

    // ===== P3: read a-low + b c1 (top); bar; MFMA lo =====
    #pragma unroll
    for (int i = 0; i < 4; ++i) {
        av[i] = *(const bf16x8*)(pa + arow + i * 1024 + c1);
        b1[i] = *(const bf16x8*)(pb + brow + i * 1024 + c1);
    }
    __builtin_amdgcn_sched_barrier(0);
    __builtin_amdgcn_s_barrier();
    asm volatile("s_waitcnt lgkmcnt(0)" ::: "memory");
    __builtin_amdgcn_sched_barrier(0);
    __builtin_amdgcn_s_setprio(1);
    #pragma unroll
    for (int mi = 0; mi < 4; ++mi)
        #pragma unroll
        for (int ni = 0; ni < 4; ++ni)
            acc[mi][ni] = __builtin_amdgcn_mfma_f32_16x16x32_bf16(av[mi], b1[ni], acc[mi][ni], 0, 0, 0);
    __builtin_amdgcn_s_setprio(0);
    __builtin_amdgcn_sched_barrier(0);

    // ===== P4: read a-high c1 (top); bar; stage 6 chunks of t+2; MFMA hi =====
    #pragma unroll
    for (int i = 0; i < 4; ++i)
        av[i] = *(const bf16x8*)(pa + arow + 4096 + i * 1024 + c1);
    __builtin_amdgcn_sched_barrier(0);
    __builtin_amdgcn_s_barrier();
    __builtin_amdgcn_sched_barrier(0);
    if (STG4) {
        gload16(gA2 + (size_t)(0 + srow) * K, lAr);                // A0
        gload16(gA2 + (size_t)(128 + srow) * K, lAr + 2 * 8192);   // A2
        gload16(gB2 + (size_t)(0 + srow) * K, lBr);                // B0
        gload16(gB2 + (size_t)(64 + srow) * K, lBr + 8192);        // B1
        gload16(gB2 + (size_t)(128 + srow) * K, lBr + 2 * 8192);   // B2
        gload16(gB2 + (size_t)(192 + srow) * K, lBr + 3 * 8192);   // B3
    }
    asm volatile("s_waitcnt lgkmcnt(0)" ::: "memory");
    __builtin_amdgcn_sched_barrier(0);
    __builtin_amdgcn_s_setprio(1);
    #pragma unroll
    for (int mi = 0; mi < 4; ++mi)
        #pragma unroll
        for (int ni = 0; ni < 4; ++ni)
            acc[4 + mi][ni] = __builtin_amdgcn_mfma_f32_16x16x32_bf16(av[mi], b1[ni], acc[4 + mi][ni], 0, 0, 0);
    __builtin_amdgcn_s_setprio(0);
    __builtin_amdgcn_sched_barrier(0);
}

__global__ __launch_bounds__(512, 2)
void gemm_bf16_kernel(const __hip_bfloat16* __restrict__ A,   // [M][K] bf16
                      const __hip_bfloat16* __restrict__ Bw,  // [N][K] bf16
                      const float* __restrict__ bias,
                      float* __restrict__ C) {                // [M][N] fp32
    constexpr int Mtiles = M_DIM / 256;            // 16
    constexpr int Ntiles = N_DIM / 256;            // 64
    constexpr int nwg = Mtiles * Ntiles;           // 1024 (div by 8)
    constexpr int NT = K_DIM / 64;                 // 64 K-tiles

    int bid = blockIdx.x;
    int swz = (bid & 7) * (nwg >> 3) + (bid >> 3);   // bijective XCD swizzle
    int bm = swz % Mtiles;
    int bn = swz / Mtiles;

    __shared__ __align__(16) __hip_bfloat16 sA[2][256 * 64];   // 64 KiB
    __shared__ __align__(16) __hip_bfloat16 sB[2][256 * 64];   // 64 KiB

    const int t = threadIdx.x;
    const int l = t & 63;
    const int w = t >> 6;        // wave 0..7
    const int wm = w >> 2;       // 0..1  (M half)
    const int wn = w & 3;        // 0..3  (N quarter)

    const int lr = l & 15;
    const int lk = l >> 4;
    const int rx = (lr & 7) << 3;          // read-side element-col XOR

    // staging (rule #21): linear LDS dest, pre-swizzled global source col.
    const int srow = w * 8 + (l >> 3);
    const int scol = ((l & 7) ^ (l >> 3)) << 3;

    const size_t K = K_DIM;
    const __hip_bfloat16* aB = A  + (size_t)(bm * 256) * K + scol;
    const __hip_bfloat16* bB = Bw + (size_t)(bn * 256) * K + scol;

    f32x4 acc[8][4] = {};

    const int c0 = (lk * 8) ^ rx;
    const int c1 = (32 + lk * 8) ^ rx;
    const int arow = (wm * 128 + lr) * 64;
    const int brow = (wn * 64 + lr) * 64;

    char* lA0 = (char*)&sA[0][0] + w * 1024;
    char* lB0 = (char*)&sB[0][0] + w * 1024;
    char* lA1 = (char*)&sA[1][0] + w * 1024;
    char* lB1 = (char*)&sB[1][0] + w * 1024;

    // prologue: tile0 all 8 chunks -> buf0; tile1 {A0,A2,B0..B3} -> buf1
    {
        #pragma unroll
        for (int j = 0; j < 4; ++j) {
            gload16(aB + (size_t)(j * 64 + srow) * K, lA0 + j * 8192);
            gload16(bB + (size_t)(j * 64 + srow) * K, lB0 + j * 8192);
        }
        const __hip_bfloat16* a1 = aB + 64;
        const __hip_bfloat16* b1 = bB + 64;
        gload16(a1 + (size_t)(0 + srow) * K, lA1);
        gload16(a1 + (size_t)(128 + srow) * K, lA1 + 2 * 8192);
        #pragma unroll
        for (int j = 0; j < 4; ++j)
            gload16(b1 + (size_t)(j * 64 + srow) * K, lB1 + j * 8192);
    }

    #pragma unroll 1
    for (int kt = 0; kt < 62; kt += 2) {
        kstep<true, true, false>(&sA[0][0], &sB[0][0],
                                 aB + (kt + 1) * 64, aB + (kt + 2) * 64, bB + (kt + 2) * 64,
                                 lA1, lA0, lB0, acc, arow, brow, c0, c1, srow);
        kstep<true, true, false>(&sA[1][0], &sB[1][0],
                                 aB + (kt + 2) * 64, aB + (kt + 3) * 64, bB + (kt + 3) * 64,
                                 lA0, lA1, lB1, acc, arow, brow, c0, c1, srow);
    }
    // kt = 62: reads buf0; stage A1,A3 of tile 63 -> buf1; no P4 stage
    kstep<true, false, false>(&sA[0][0], &sB[0][0],
                              aB + 63 * 64, aB, bB,
                              lA1, lA0, lB0, acc, arow, brow, c0, c1, srow);
    // kt = 63: reads buf1; vmcnt(0)
    kstep<false, false, true>(&sA[1][0], &sB[1][0],
                              aB, aB, bB,
                              lA0, lA1, lB1, acc, arow, brow, c0, c1, srow);

    // epilogue: C/D layout col=lane&15, row=(lane>>4)*4+reg  [m89-verified]
    const int crow0 = bm * 256 + wm * 128;
    const int ccol0 = bn * 256 + wn * 64;
    #pragma unroll
    for (int ni = 0; ni < 4; ++ni) {
        int col = ccol0 + ni * 16 + lr;
        float bv = bias[col];
        #pragma unroll
        for (int mi = 0; mi < 8; ++mi) {
            int rbase = crow0 + mi * 16 + lk * 4;
            #pragma unroll
            for (int j = 0; j < 4; ++j) {
                C[(size_t)(rbase + j) * N_DIM + col] = acc[mi][ni][j] + bv;
            }
        }
    }
}

// ---------- fallback (ws too small): fp32 LDS-tiled, correct but slow ----------
__global__ __launch_bounds__(256)
void gemm_fallback(const float* __restrict__ X, const float* __restrict__ W,
                   const float* __restrict__ scale, const float* __restrict__ bias,
                   float* __restrict__ C) {
    int bm = blockIdx.x % (M_DIM / 64);
    int bn = blockIdx.x / (M_DIM / 64);
    __shared__ float sA[64][33];
    __shared__ float sB[64][33];
    int t = threadIdx.x;
    int tx = t & 15, ty = t >> 4;
    float acc[4][4] = {};
    for (int kt = 0; kt < K_DIM / 32; ++kt) {
        float s = scale[(bn >> 1) * (K_DIM / 128) + (kt >> 2)];
        #pragma unroll
        for (int i = 0; i < 8; ++i) {
            int idx = t + i * 256;
            int r = idx >> 5, c = idx & 31;
            sA[r][c] = X[(size_t)(bm * 64 + r) * K_DIM + kt * 32 + c];
            sB[r][c] = W[(size_t)(bn * 64 + r) * K_DIM + kt * 32 + c] * s;
        }
        __syncthreads();
        #pragma unroll
        for (int k = 0; k < 32; ++k) {
            float a[4], b[4];
            #pragma unroll
            for (int i = 0; i < 4; ++i) a[i] = sA[ty * 4 + i][k];
            #pragma unroll
            for (int j = 0; j < 4; ++j) b[j] = sB[tx * 4 + j][k];
            #pragma unroll
            for (int i = 0; i < 4; ++i)
                #pragma unroll
                for (int j = 0; j < 4; ++j) acc[i][j] += a[i] * b[j];
        }
        __syncthreads();
    }
    #pragma unroll
    for (int i = 0; i < 4; ++i)
        #pragma unroll
        for (int j = 0; j < 4; ++j) {
            int row = bm * 64 + ty * 4 + i;
            int col = bn * 64 + tx * 4 + j;
            C[(size_t)row * N_DIM + col] = acc[i][j] + bias[col];
        }
}

extern "C" void kernel_launch(void* const* d_in, const int* in_sizes, int n_in,
                              void* d_out, int out_size, void* d_ws, size_t ws_size,
                              hipStream_t stream) {
    const float* x     = (const float*)d_in[0];   // [2,2048,4096]
    const float* wgt   = (const float*)d_in[1];   // [16384,4096]
    const float* scale = (const float*)d_in[2];   // [128,32]
    const float* bias  = (const float*)d_in[3];   // [16384]
    float* out = (float*)d_out;                   // [2,2048,16384]

    const size_t need = ((size_t)M_DIM * K_DIM + (size_t)N_DIM * K_DIM) * sizeof(__hip_bfloat16);
    if (ws_size >= need) {
        __hip_bfloat16* xbf = (__hip_bfloat16*)d_ws;
        __hip_bfloat16* wbf = xbf + (size_t)M_DIM * K_DIM;
        cvt_x_kernel<<<2048, 256, 0, stream>>>(x, xbf, M_DIM * K_DIM / 8);
        dequant_w_kernel<<<4096, 256, 0, stream>>>(wgt, scale, wbf);
        gemm_bf16_kernel<<<(M_DIM / 256) * (N_DIM / 256), 512, 0, stream>>>(xbf, wbf, bias, out);
    } else {
        gemm_fallback<<<(M_DIM / 64) * (N_DIM / 64), 256, 0, stream>>>(x, wgt, scale, bias, out);
    }
}